// Round 1
// 575.534 us; speedup vs baseline: 1.1226x; 1.1226x over previous
//
#include <hip/hip_runtime.h>
#include <hip/hip_fp16.h>

#define RL(x) __builtin_amdgcn_readfirstlane(x)

// ---------------- weight prep ----------------
// wt1n[(ic*8+ky)*256 + g*64 + j*8 + kx] = w1[(g*8+j)*256 + ic*64 + ky*8 + kx]   (8192)
// wt2n[((ic*4+ky)*8+ocg)*32 + o*4+kx]  = w2[(ocg*8+o)*512 + ic*16 + ky*4 + kx] (32768)
// wt3n[((ic*3+ky)*8+ocg)*24 + o*3+kx]  = w3[(ocg*8+o)*576 + ic*9  + ky*3 + kx] (36864)
__global__ __launch_bounds__(256) void wprep_k(const float* __restrict__ w1,
                                               const float* __restrict__ w2,
                                               const float* __restrict__ w3,
                                               float* __restrict__ wt1,
                                               float* __restrict__ wt2,
                                               float* __restrict__ wt3) {
  int i = blockIdx.x * 256 + threadIdx.x;
  if (i < 8192) {
    int kx = i & 7, j = (i >> 3) & 7, g = (i >> 6) & 3;
    int ky = (i >> 8) & 7, ic = i >> 11;
    wt1[i] = w1[(g * 8 + j) * 256 + ic * 64 + ky * 8 + kx];
  }
  if (i < 32768) {
    int o4 = i & 31, o = o4 >> 2, kx = o4 & 3;
    int r = i >> 5, ocg = r & 7, r2 = r >> 3, ky = r2 & 3, ic = r2 >> 2;
    wt2[i] = w2[(ocg * 8 + o) * 512 + ic * 16 + ky * 4 + kx];
  }
  if (i < 36864) {
    int o3 = i % 24, o = o3 / 3, kx = o3 - o * 3;
    int r = i / 24, ocg = r & 7, r2 = r >> 3, ky = r2 % 3, ic = r2 / 3;
    wt3[i] = w3[(ocg * 8 + o) * 576 + ic * 9 + ky * 3 + kx];
  }
}

// ---------------- conv1: x[1024,4,84,84] -> c1h[b][32*400] fp16, k=8, s=4 ----------------
// Pixels on lanes. Weights now wave-uniform s_loads from wt1n (SGPR FMA operand):
// no LDS staging, no barrier, lower VGPR pressure -> more resident waves.
__global__ __launch_bounds__(256, 4) void conv1_k(const float* __restrict__ x,
                                                  const float* __restrict__ wt,   // wt1n
                                                  const float* __restrict__ bias,
                                                  __half* __restrict__ out) {
  const int b    = blockIdx.x;
  const int tid  = threadIdx.x;
  const int lane = tid & 63;
  const int g    = RL(tid >> 6);

  int pv[7], ib[7];
#pragma unroll
  for (int s = 0; s < 7; ++s) {
    int p = lane + 64 * s;
    pv[s] = (p < 400);
    if (p > 399) p = 399;
    int py = p / 20, px = p - py * 20;
    ib[s] = py * 336 + px * 4;
  }

  float acc[7][8];
#pragma unroll
  for (int s = 0; s < 7; ++s)
#pragma unroll
    for (int j = 0; j < 8; ++j) acc[s][j] = 0.f;

  const float* xb = x + b * 28224;
#pragma unroll 1
  for (int ic = 0; ic < 4; ++ic) {
#pragma unroll 1
    for (int ky = 0; ky < 8; ++ky) {
      const float* wp = wt + (ic * 8 + ky) * 256 + g * 64;   // uniform -> s_load
      float wr[8][8];
#pragma unroll
      for (int j = 0; j < 8; ++j) {
        float4 w0 = *(const float4*)(wp + j * 8);
        float4 w1 = *(const float4*)(wp + j * 8 + 4);
        wr[j][0]=w0.x; wr[j][1]=w0.y; wr[j][2]=w0.z; wr[j][3]=w0.w;
        wr[j][4]=w1.x; wr[j][5]=w1.y; wr[j][6]=w1.z; wr[j][7]=w1.w;
      }
      const float* rp = xb + ic * 7056 + ky * 84;
#pragma unroll
      for (int s = 0; s < 7; ++s) {
        float4 a = *(const float4*)(rp + ib[s]);
        float4 c = *(const float4*)(rp + ib[s] + 4);
        float in8[8] = {a.x, a.y, a.z, a.w, c.x, c.y, c.z, c.w};
#pragma unroll
        for (int j = 0; j < 8; ++j)
#pragma unroll
          for (int kx = 0; kx < 8; ++kx)
            acc[s][j] = fmaf(in8[kx], wr[j][kx], acc[s][j]);
      }
    }
  }

  const float inv256 = 1.0f / 256.0f;
#pragma unroll
  for (int j = 0; j < 8; ++j) {
    float bj = bias[g * 8 + j];
    __half* op = out + (b * 32 + g * 8 + j) * 400;
#pragma unroll
    for (int s = 0; s < 7; ++s) {
      if (pv[s]) {
        float v = acc[s][j] * inv256 + bj;
        op[lane + 64 * s] = __float2half(v > 0.f ? v : 0.f);
      }
    }
  }
}

// ---------------- t1: transpose c1h[1024][12800] -> c1t[12800][1024] (fp16) ----------------
__global__ __launch_bounds__(256) void t1_k(const __half* __restrict__ in,
                                            __half* __restrict__ out) {
  __shared__ __half t[64][65];
  const int kb = blockIdx.x * 64;   // 200 tiles
  const int bb = blockIdx.y * 64;   // 16 tiles
  const int lane = threadIdx.x & 63;
  const int ty   = threadIdx.x >> 6;
#pragma unroll
  for (int r = ty; r < 64; r += 4)
    t[r][lane] = in[(bb + r) * 12800 + kb + lane];
  __syncthreads();
#pragma unroll
  for (int r = ty; r < 64; r += 4)
    out[(kb + r) * 1024 + bb + lane] = t[lane][r];
}

// ---------------- conv2: c1t[12800][1024] -> c2t[5184][1024], k=4, s=2 (fp16 io) ----------
// Batch on lanes. oc-group split 8->16 (4 oc/wave) for 2x wave-level parallelism.
__global__ __launch_bounds__(64, 2) void conv2_k(const __half* __restrict__ in,
                                                 const float* __restrict__ wt,   // wt2n
                                                 const float* __restrict__ bias,
                                                 __half* __restrict__ out) {
  const int bid = blockIdx.x;            // 2304 = (bg*9 + opy)*16 + ocg
  const int ocg = bid & 15;              // 16 groups of 4 oc
  const int r   = bid >> 4;
  const int opy = r % 9;
  const int bg  = r / 9;
  const int lane = threadIdx.x;

  float acc[4][9];
#pragma unroll
  for (int o = 0; o < 4; ++o)
#pragma unroll
    for (int ox = 0; ox < 9; ++ox) acc[o][ox] = 0.f;

  const __half* ib = in + bg * 64 + lane;

#pragma unroll 1
  for (int ic = 0; ic < 32; ++ic) {
#pragma unroll
    for (int ky = 0; ky < 4; ++ky) {
      const float* wp = wt + ((ic * 4 + ky) * 8 + (ocg >> 1)) * 32 + (ocg & 1) * 16;
      float wk[16];
#pragma unroll
      for (int q = 0; q < 16; ++q) wk[q] = wp[q];
      const __half* rp = ib + (ic * 400 + (2 * opy + ky) * 20) * 1024;
      float iv[20];
#pragma unroll
      for (int q = 0; q < 20; ++q) iv[q] = __half2float(rp[q * 1024]);
#pragma unroll
      for (int o = 0; o < 4; ++o)
#pragma unroll
        for (int ox = 0; ox < 9; ++ox)
#pragma unroll
          for (int kx = 0; kx < 4; ++kx)
            acc[o][ox] = fmaf(iv[2 * ox + kx], wk[o * 4 + kx], acc[o][ox]);
    }
  }

#pragma unroll
  for (int o = 0; o < 4; ++o) {
    const int oc = ocg * 4 + o;
    const float bj = bias[oc];
#pragma unroll
    for (int ox = 0; ox < 9; ++ox) {
      float v = acc[o][ox] + bj;
      out[(oc * 81 + opy * 9 + ox) * 1024 + bg * 64 + lane] =
          __float2half(v > 0.f ? v : 0.f);
    }
  }
}

// ---------------- conv3: c2t[5184][1024] -> c3t[3136][1024], k=3, s=1 (fp16 io) ----------
__global__ __launch_bounds__(64, 2) void conv3_k(const __half* __restrict__ in,
                                                 const float* __restrict__ wt,   // wt3n
                                                 const float* __restrict__ bias,
                                                 __half* __restrict__ out) {
  const int bid = blockIdx.x;            // 1792 = (bg*7 + opy)*16 + ocg
  const int ocg = bid & 15;              // 16 groups of 4 oc
  const int r   = bid >> 4;
  const int opy = r % 7;
  const int bg  = r / 7;
  const int lane = threadIdx.x;

  float acc[4][7];
#pragma unroll
  for (int o = 0; o < 4; ++o)
#pragma unroll
    for (int ox = 0; ox < 7; ++ox) acc[o][ox] = 0.f;

  const __half* ib = in + bg * 64 + lane;

#pragma unroll 1
  for (int ic = 0; ic < 64; ++ic) {
#pragma unroll
    for (int ky = 0; ky < 3; ++ky) {
      const float* wp = wt + ((ic * 3 + ky) * 8 + (ocg >> 1)) * 24 + (ocg & 1) * 12;
      float wk[12];
#pragma unroll
      for (int q = 0; q < 12; ++q) wk[q] = wp[q];
      const __half* rp = ib + (ic * 81 + (opy + ky) * 9) * 1024;
      float iv[9];
#pragma unroll
      for (int q = 0; q < 9; ++q) iv[q] = __half2float(rp[q * 1024]);
#pragma unroll
      for (int o = 0; o < 4; ++o)
#pragma unroll
        for (int ox = 0; ox < 7; ++ox)
#pragma unroll
          for (int kx = 0; kx < 3; ++kx)
            acc[o][ox] = fmaf(iv[ox + kx], wk[o * 3 + kx], acc[o][ox]);
    }
  }

#pragma unroll
  for (int o = 0; o < 4; ++o) {
    const int oc = ocg * 4 + o;
    const float bj = bias[oc];
#pragma unroll
    for (int ox = 0; ox < 7; ++ox) {
      float v = acc[o][ox] + bj;
      out[(oc * 49 + opy * 7 + ox) * 1024 + bg * 64 + lane] =
          __float2half(v > 0.f ? v : 0.f);
    }
  }
}

// ---------------- fc1a: c3t[3136][1024] @ fw1[3136][256] -> part[8][256][1024] ------------
__global__ __launch_bounds__(64, 2) void fc1a_k(const __half* __restrict__ a,
                                                const float* __restrict__ w,
                                                float* __restrict__ part) {
  const int bid = blockIdx.x;            // 2048 = (bg*16 + jg)*8 + kc
  const int kc = bid & 7;
  const int r  = bid >> 3;
  const int jg = r & 15;
  const int bg = r >> 4;
  const int lane = threadIdx.x;

  float acc[16];
#pragma unroll
  for (int j = 0; j < 16; ++j) acc[j] = 0.f;

  const __half* ap = a + kc * 392 * 1024 + bg * 64 + lane;
  const float* wp0 = w + kc * 392 * 256 + jg * 16;

#pragma unroll 4
  for (int k = 0; k < 392; ++k) {
    float av = __half2float(ap[k * 1024]);
    const float* wp = wp0 + k * 256;
#pragma unroll
    for (int j = 0; j < 16; ++j) acc[j] = fmaf(av, wp[j], acc[j]);
  }
#pragma unroll
  for (int j = 0; j < 16; ++j)
    part[(kc * 256 + jg * 16 + j) * 1024 + bg * 64 + lane] = acc[j];
}

// ---------------- fc1b: reduce 8 partials + bias + relu -> h_t[256][1024] ----------------
__global__ __launch_bounds__(256) void fc1b_k(const float* __restrict__ part,
                                              const float* __restrict__ bias,
                                              float* __restrict__ h) {
  int idx = blockIdx.x * 256 + threadIdx.x;   // j*1024 + b
  float s = bias[idx >> 10];
#pragma unroll
  for (int c = 0; c < 8; ++c) s += part[c * 262144 + idx];
  h[idx] = s > 0.f ? s : 0.f;
}

// ---------------- fc2 + softmax + dist/res (reads h_t[k][b]) ----------------
__global__ __launch_bounds__(256) void fc2_k(const float* __restrict__ h,     // [256][1024]
                                             const float* __restrict__ w,     // [256][51]
                                             const float* __restrict__ bias,
                                             const float* __restrict__ z,
                                             float* __restrict__ dist,        // [1024][6][51]
                                             float* __restrict__ res) {       // [1024][6]
  const int tid = threadIdx.x;
  const int j   = tid & 63;
  const int b   = blockIdx.x * 4 + RL(tid >> 6);
  const int jc = j < 51 ? j : 50;
  float acc = bias[jc];
#pragma unroll 4
  for (int k = 0; k < 256; ++k)
    acc = fmaf(h[k * 1024 + b], w[k * 51 + jc], acc);
  float logit = (j < 51) ? acc : -1e30f;
  float m = logit;
#pragma unroll
  for (int o = 32; o > 0; o >>= 1) m = fmaxf(m, __shfl_xor(m, o, 64));
  float e = (j < 51) ? __expf(logit - m) : 0.f;
  float ssum = e;
#pragma unroll
  for (int o = 32; o > 0; o >>= 1) ssum += __shfl_xor(ssum, o, 64);
  float p = e / ssum;
  float zv = (j < 51) ? z[jc] : 0.f;
  float rz = p * zv;
#pragma unroll
  for (int o = 32; o > 0; o >>= 1) rz += __shfl_xor(rz, o, 64);
  if (j < 51) {
    float* db = dist + b * 6 * 51 + j;
#pragma unroll
    for (int n = 0; n < 6; ++n) db[n * 51] = p;
  }
  if (j < 6) res[b * 6 + j] = rz;
}

extern "C" void kernel_launch(void* const* d_in, const int* in_sizes, int n_in,
                              void* d_out, int out_size, void* d_ws, size_t ws_size,
                              hipStream_t stream) {
  const float* x   = (const float*)d_in[0];
  const float* cw1 = (const float*)d_in[1];
  const float* cb1 = (const float*)d_in[2];
  const float* cw2 = (const float*)d_in[3];
  const float* cb2 = (const float*)d_in[4];
  const float* cw3 = (const float*)d_in[5];
  const float* cb3 = (const float*)d_in[6];
  const float* fw1 = (const float*)d_in[7];
  const float* fb1 = (const float*)d_in[8];
  const float* fw2 = (const float*)d_in[9];
  const float* fb2 = (const float*)d_in[10];
  const float* z   = (const float*)d_in[11];

  float* ws = (float*)d_ws;
  // float-offsets (fp16 buffers occupy half):
  // c1h : [0, 6553600)          1024*12800 halfs
  // c1t : [6553600, 13107200)   12800*1024 halfs
  // c2t : [13107200, 15761408)  5184*1024 halfs
  // c3t : [15761408, 17367040)  3136*1024 halfs
  // part: [0, 2097152)          8*256*1024 fp32 (reuses dead c1h)
  // h_t : [2097152, 2359296)    256*1024 fp32
  __half* c1h = (__half*)ws;
  __half* c1t = (__half*)(ws + 6553600);
  __half* c2t = (__half*)(ws + 13107200);
  __half* c3t = (__half*)(ws + 15761408);
  float*  pw  = ws;
  float*  h_t = ws + 2097152;

  // Transposed conv weights in d_out scratch (77824 <= 319488); dist written last.
  float* wt2n = (float*)d_out;
  float* wt3n = (float*)d_out + 32768;
  float* wt1n = (float*)d_out + 69632;

  float* dist = (float*)d_out;
  float* res  = dist + 1024 * 6 * 51;

  wprep_k<<<144, 256, 0, stream>>>(cw1, cw2, cw3, wt1n, wt2n, wt3n);
  conv1_k<<<1024, 256, 0, stream>>>(x, wt1n, cb1, c1h);
  t1_k<<<dim3(200, 16), 256, 0, stream>>>(c1h, c1t);
  conv2_k<<<2304, 64, 0, stream>>>(c1t, wt2n, cb2, c2t);
  conv3_k<<<1792, 64, 0, stream>>>(c2t, wt3n, cb3, c3t);
  fc1a_k<<<2048, 64, 0, stream>>>(c3t, fw1, pw);
  fc1b_k<<<1024, 256, 0, stream>>>(pw, fb1, h_t);
  fc2_k<<<256, 256, 0, stream>>>(h_t, fw2, fb2, z, dist, res);
}